// Round 2
// baseline (511.340 us; speedup 1.0000x reference)
//
#include <hip/hip_runtime.h>
#include <math.h>

// Problem constants (from setup_inputs): B=16384 rows, C=4096 cols, NBINS=1000.
constexpr int BROWS = 16384;
constexpr int CCOLS = 4096;
constexpr int BLOCK = 512;                 // 8 waves/block, one row at a time
constexpr int WAVES = BLOCK / 64;          // 8
constexpr int RPB   = 16;                  // rows per block (software pipeline depth)
constexpr int GRID  = BROWS / RPB;         // 1024 blocks = 4 blocks/CU, all resident
constexpr int V4PT  = CCOLS / BLOCK / 4;   // 2 float4 per thread per array per row
constexpr int EPT   = 4 * V4PT;            // 8 elements per thread per row

// base-2 formulation: v_exp_f32/v_log_f32 are natively base-2 on gfx9.
constexpr float INV_LN2      = 1.4426950408889634f;
constexpr float LN2          = 0.6931471805599453f;
constexpr float LOG2_EPS     = -23.253496664211536f;  // log2(1e-7)
constexpr float LOG2_1M_EPS  = -1.4426951e-7f;        // log2(1 - 1e-7)

__device__ __forceinline__ float fast_exp2(float x) {
#if __has_builtin(__builtin_amdgcn_exp2f)
    return __builtin_amdgcn_exp2f(x);
#else
    return __expf(x * LN2);
#endif
}
__device__ __forceinline__ float fast_log2(float x) {
#if __has_builtin(__builtin_amdgcn_logf)
    return __builtin_amdgcn_logf(x);   // log base 2
#else
    return __log2f(x);
#endif
}

__device__ __forceinline__ float wave_reduce_sum(float v) {
#pragma unroll
    for (int m = 32; m > 0; m >>= 1) v += __shfl_xor(v, m, 64);
    return v;
}
__device__ __forceinline__ float wave_reduce_max(float v) {
#pragma unroll
    for (int m = 32; m > 0; m >>= 1) v = fmaxf(v, __shfl_xor(v, m, 64));
    return v;
}
__device__ __forceinline__ double wave_reduce_sum_d(double v) {
#pragma unroll
    for (int m = 32; m > 0; m >>= 1) v += __shfl_xor(v, m, 64);
    return v;
}

// -(bce term) in base-2 units: y*log2(clip p) + (1-y)*log2(clip(1-p)).
// x2 = x*INV_LN2, off2 = log2(softmax denominator) + m2.
// NaN from log2(1-p) when p rounds >1 resolves to LOG2_EPS via fmaxf (IEEE: returns non-NaN).
__device__ __forceinline__ float nbce2(float x2, float y, float off2) {
    float z2 = x2 - off2;                                   // log2 softmax
    float zc = fminf(fmaxf(z2, LOG2_EPS), LOG2_1M_EPS);     // log2(clip(p))
    float p  = fast_exp2(z2);
    float l2 = fast_log2(1.0f - p);                         // log2(1-p)
    l2 = fminf(fmaxf(l2, LOG2_EPS), LOG2_1M_EPS);           // log2(clip(1-p)) both edges
    return fmaf(y, zc - l2, l2);                            // y*zc + (1-y)*l2
}

__global__ void __launch_bounds__(BLOCK, 8)   // cap VGPR<=64 -> 8 waves/SIMD
wce_main_kernel(const float* __restrict__ y_pred,
                const float* __restrict__ y_true,
                const float* __restrict__ weights,
                const int*   __restrict__ cond,
                float* __restrict__ partials)   // [BROWS] per-row weighted bce sums
{
    __shared__ float2 s_ms[WAVES];   // (m2_w, s_w) per wave
    __shared__ float  s_nb[WAVES];

    const int tid  = threadIdx.x;
    const int wave = tid >> 6;
    const int lane = tid & 63;
    const int row0 = blockIdx.x * RPB;

    // double-buffered per-row register tiles (statically indexed after full unroll)
    float4 v[2][V4PT];
    float4 t[2][V4PT];

    // ---- prologue: issue row0 loads ----
    {
        const float4* yp4 = (const float4*)(y_pred + (size_t)row0 * CCOLS);
        const float4* yt4 = (const float4*)(y_true + (size_t)row0 * CCOLS);
#pragma unroll
        for (int i = 0; i < V4PT; ++i) v[0][i] = yp4[tid + BLOCK * i];
#pragma unroll
        for (int i = 0; i < V4PT; ++i) t[0][i] = yt4[tid + BLOCK * i];
    }

#pragma unroll
    for (int r = 0; r < RPB; ++r) {
        const int cur = r & 1;
        const int nxt = cur ^ 1;
        const int row = row0 + r;

        // ---- prefetch row r+1 while row r computes (hides HBM latency) ----
        if (r + 1 < RPB) {
            const float4* yp4 = (const float4*)(y_pred + (size_t)(row + 1) * CCOLS);
            const float4* yt4 = (const float4*)(y_true + (size_t)(row + 1) * CCOLS);
#pragma unroll
            for (int i = 0; i < V4PT; ++i) v[nxt][i] = yp4[tid + BLOCK * i];
#pragma unroll
            for (int i = 0; i < V4PT; ++i) t[nxt][i] = yt4[tid + BLOCK * i];
        }

        // ---- pass 1: convert to base-2, wave-local max ----
        float x2[EPT];
        float m2w = -3.4e38f;
#pragma unroll
        for (int i = 0; i < V4PT; ++i) {
            x2[4*i+0] = v[cur][i].x * INV_LN2;
            x2[4*i+1] = v[cur][i].y * INV_LN2;
            x2[4*i+2] = v[cur][i].z * INV_LN2;
            x2[4*i+3] = v[cur][i].w * INV_LN2;
            m2w = fmaxf(m2w, fmaxf(fmaxf(x2[4*i+0], x2[4*i+1]),
                                   fmaxf(x2[4*i+2], x2[4*i+3])));
        }
        m2w = wave_reduce_max(m2w);

        // ---- pass 2: wave-local sum of 2^(x2 - m2w) ----
        float s2w = 0.0f;
#pragma unroll
        for (int i = 0; i < EPT; ++i) s2w += fast_exp2(x2[i] - m2w);
        s2w = wave_reduce_sum(s2w);
        if (lane == 0) s_ms[wave] = make_float2(m2w, s2w);
        __syncthreads();   // barrier 1: publish per-wave (max, sum)

        // ---- combine per-wave pairs (redundantly, all threads; no 2nd barrier) ----
        float2 msl[WAVES];
        float  m2 = -3.4e38f;
#pragma unroll
        for (int i = 0; i < WAVES; ++i) { msl[i] = s_ms[i]; m2 = fmaxf(m2, msl[i].x); }
        float s = 0.0f;
#pragma unroll
        for (int i = 0; i < WAVES; ++i) s += msl[i].y * fast_exp2(msl[i].x - m2);
        const float off2 = m2 + fast_log2(s);   // log2-softmax offset

        // ---- pass 3: clipped BCE from registers ----
        float nb = 0.0f;
#pragma unroll
        for (int i = 0; i < V4PT; ++i) {
            const float4 tt = t[cur][i];
            nb += nbce2(x2[4*i+0], tt.x, off2);
            nb += nbce2(x2[4*i+1], tt.y, off2);
            nb += nbce2(x2[4*i+2], tt.z, off2);
            nb += nbce2(x2[4*i+3], tt.w, off2);
        }
        nb = wave_reduce_sum(nb);
        if (lane == 0) s_nb[wave] = nb;
        __syncthreads();   // barrier 2: publish per-wave bce sums

        if (tid == 0) {
            float rnb = s_nb[0];
#pragma unroll
            for (int i = 1; i < WAVES; ++i) rnb += s_nb[i];
            const float w = weights[cond[row]];
            partials[row] = -w * LN2 * rnb;   // positive weighted bce, back to nat-log units
        }
    }
}

// Reduce BROWS partials (f32) in double, divide, write the scalar loss.
__global__ void __launch_bounds__(256)
wce_reduce_kernel(const float* __restrict__ partials, float* __restrict__ out)
{
    __shared__ double s_part[4];
    const int tid  = threadIdx.x;
    const int wave = tid >> 6;
    const int lane = tid & 63;

    const float4* p4 = (const float4*)partials;
    double s = 0.0;
#pragma unroll
    for (int i = 0; i < BROWS / (256 * 4); ++i) {   // 16 iters
        float4 p = p4[tid + 256 * i];
        s += (double)p.x + (double)p.y + (double)p.z + (double)p.w;
    }
    s = wave_reduce_sum_d(s);
    if (lane == 0) s_part[wave] = s;
    __syncthreads();
    if (tid == 0) {
        double total = (s_part[0] + s_part[1]) + (s_part[2] + s_part[3]);
        out[0] = (float)(total / ((double)BROWS * (double)CCOLS));
    }
}

extern "C" void kernel_launch(void* const* d_in, const int* in_sizes, int n_in,
                              void* d_out, int out_size, void* d_ws, size_t ws_size,
                              hipStream_t stream) {
    const float* y_pred  = (const float*)d_in[0];
    const float* y_true  = (const float*)d_in[1];
    const float* weights = (const float*)d_in[2];
    const int*   cond    = (const int*)d_in[3];
    float* out      = (float*)d_out;
    float* partials = (float*)d_ws;   // BROWS floats = 64 KB scratch

    wce_main_kernel<<<GRID, BLOCK, 0, stream>>>(y_pred, y_true, weights, cond, partials);
    wce_reduce_kernel<<<1, 256, 0, stream>>>(partials, out);
}